// Round 1
// baseline (601.392 us; speedup 1.0000x reference)
//
#include <hip/hip_runtime.h>
#include <hip/hip_bf16.h>

#define N_NODES 40000
#define N_EDGES 640000
#define NFEAT 128
#define NGRAPHS 64

typedef __attribute__((ext_vector_type(8))) short short8;
typedef __attribute__((ext_vector_type(4))) float float4v;

static __device__ __forceinline__ float bf2f(unsigned short u) {
    unsigned int x = ((unsigned int)u) << 16;
    return __builtin_bit_cast(float, x);
}
static __device__ __forceinline__ unsigned short f2bf(float f) {
    unsigned int x = __builtin_bit_cast(unsigned int, f);
    unsigned int r = x + 0x7fffu + ((x >> 16) & 1u);
    return (unsigned short)(r >> 16);
}

// ---------------- CSR build ----------------
__global__ void k_count(const int* __restrict__ dst, int* __restrict__ deg) {
    int e = blockIdx.x * 256 + threadIdx.x;
    if (e < N_EDGES) atomicAdd(&deg[dst[e]], 1);
}

__global__ void k_scan(const int* __restrict__ deg, int* __restrict__ offsets,
                       int* __restrict__ cursor) {
    __shared__ int buf[256];
    __shared__ int s_run;
    int tid = threadIdx.x;
    if (tid == 0) s_run = 0;
    __syncthreads();
    for (int base = 0; base < N_NODES; base += 256) {
        int i = base + tid;
        int v = (i < N_NODES) ? deg[i] : 0;
        buf[tid] = v;
        __syncthreads();
        for (int d = 1; d < 256; d <<= 1) {
            int t = (tid >= d) ? buf[tid - d] : 0;
            __syncthreads();
            buf[tid] += t;
            __syncthreads();
        }
        int run = s_run;
        int incl = run + buf[tid];
        if (i < N_NODES) {
            offsets[i] = incl - v;
            cursor[i]  = incl - v;
            if (i == N_NODES - 1) offsets[N_NODES] = incl;
        }
        __syncthreads();
        if (tid == 255) s_run = run + buf[255];
        __syncthreads();
    }
}

__global__ void k_fill(const int* __restrict__ src, const int* __restrict__ dst,
                       int* __restrict__ cursor, int* __restrict__ esrc) {
    int e = blockIdx.x * 256 + threadIdx.x;
    if (e < N_EDGES) {
        int d = dst[e];
        int p = atomicAdd(&cursor[d], 1);
        esrc[p] = src[e];
    }
}

// ---------------- dtype prep ----------------
__global__ void k_castx(const float* __restrict__ x, unsigned short* __restrict__ h0) {
    int i = blockIdx.x * 256 + threadIdx.x;   // index over pairs
    const int n = N_NODES * NFEAT / 2;
    if (i < n) {
        float a = x[2 * i], b = x[2 * i + 1];
        unsigned int u = (unsigned int)f2bf(a) | ((unsigned int)f2bf(b) << 16);
        ((unsigned int*)h0)[i] = u;
    }
}

// Wt layout per layer: Wt[n][k] = Wcat[k][n], n in [0,128), k in [0,256)
// k<128 -> Wl[k][n], k>=128 -> Wr[k-128][n]
__global__ void k_castw(const float* __restrict__ Wl0, const float* __restrict__ Wr0,
                        const float* __restrict__ Wl1, const float* __restrict__ Wr1,
                        const float* __restrict__ Wl2, const float* __restrict__ Wr2,
                        unsigned short* __restrict__ Wt) {
    int id = blockIdx.x * 256 + threadIdx.x;
    if (id >= 3 * 128 * 256) return;
    int l   = id >> 15;
    int rem = id & 32767;
    int nn  = rem >> 8;
    int k   = rem & 255;
    const float* Wl = (l == 0) ? Wl0 : (l == 1) ? Wl1 : Wl2;
    const float* Wr = (l == 0) ? Wr0 : (l == 1) ? Wr1 : Wr2;
    float v = (k < 128) ? Wl[k * 128 + nn] : Wr[(k - 128) * 128 + nn];
    Wt[id] = f2bf(v);
}

// ---------------- mean aggregation (one wave per node) ----------------
__global__ void k_agg(const unsigned short* __restrict__ hin,
                      const int* __restrict__ offsets,
                      const int* __restrict__ esrc,
                      unsigned short* __restrict__ agg) {
    int wave = threadIdx.x >> 6;
    int lane = threadIdx.x & 63;
    int node = blockIdx.x * 4 + wave;
    if (node >= N_NODES) return;
    int beg = offsets[node], end = offsets[node + 1];
    float a0 = 0.f, a1 = 0.f;
    const unsigned int* base = (const unsigned int*)hin;
    for (int j = beg; j < end; ++j) {
        int s = esrc[j];
        unsigned int u = base[s * 64 + lane];
        a0 += bf2f((unsigned short)(u & 0xffffu));
        a1 += bf2f((unsigned short)(u >> 16));
    }
    int d = end - beg;
    float inv = 1.f / (float)(d > 1 ? d : 1);
    unsigned int o = (unsigned int)f2bf(a0 * inv) | ((unsigned int)f2bf(a1 * inv) << 16);
    ((unsigned int*)agg)[node * 64 + lane] = o;
}

// ---------------- fused SAGE GEMM: hout = relu([agg|hin] @ [Wl;Wr] + b) ------
// block = 256 threads (4 waves), tile = 64 rows x 128 cols, K = 256
__global__ void k_gemm(const unsigned short* __restrict__ agg,
                       const unsigned short* __restrict__ hin,
                       const unsigned short* __restrict__ Wt,   // [128][256] (n-major)
                       const float* __restrict__ bias,
                       unsigned short* __restrict__ hout) {
    __shared__ __align__(16) unsigned short As[64][264];  // pad: stride 528B -> free 2-way
    int tid = threadIdx.x;
    int row0 = blockIdx.x * 64;

    // stage A = [agg | hin] tile into LDS
    {
        int c  = tid & 31;   // 16B chunk within 512B row
        int r0 = tid >> 5;   // 0..7
        for (int p = 0; p < 8; ++p) {
            int r = r0 + p * 8;
            int grow = row0 + r;
            const unsigned short* srcp = (c < 16) ? (agg + (size_t)grow * 128 + c * 8)
                                                  : (hin + (size_t)grow * 128 + (c - 16) * 8);
            uint4 v = *(const uint4*)srcp;
            *(uint4*)(&As[r][c * 8]) = v;
        }
    }
    __syncthreads();

    int wave = tid >> 6, lane = tid & 63;
    int quad = lane >> 4, l16 = lane & 15;
    float4v acc[4][2];
    for (int rt = 0; rt < 4; ++rt)
        for (int ct = 0; ct < 2; ++ct) acc[rt][ct] = {0.f, 0.f, 0.f, 0.f};

    int ncol0 = wave * 32;
    for (int kc = 0; kc < 8; ++kc) {
        int k0 = kc * 32 + quad * 8;
        short8 a[4], b[2];
        for (int rt = 0; rt < 4; ++rt)
            a[rt] = *(const short8*)(&As[rt * 16 + l16][k0]);
        for (int ct = 0; ct < 2; ++ct)
            b[ct] = *(const short8*)(Wt + (size_t)(ncol0 + ct * 16 + l16) * 256 + k0);
        for (int rt = 0; rt < 4; ++rt)
            for (int ct = 0; ct < 2; ++ct)
                acc[rt][ct] = __builtin_amdgcn_mfma_f32_16x16x32_bf16(
                    a[rt], b[ct], acc[rt][ct], 0, 0, 0);
    }

    for (int ct = 0; ct < 2; ++ct) {
        int col = ncol0 + ct * 16 + l16;
        float bv = bias[col];
        for (int rt = 0; rt < 4; ++rt) {
            int r0 = rt * 16 + quad * 4;
            for (int i = 0; i < 4; ++i) {
                float v = acc[rt][ct][i] + bv;
                v = v > 0.f ? v : 0.f;
                hout[(size_t)(row0 + r0 + i) * 128 + col] = f2bf(v);
            }
        }
    }
}

// ---------------- pooling: segment_sum(concat(h1,h2,h3), batch) ----------------
__global__ void k_pool(const unsigned short* __restrict__ h1,
                       const unsigned short* __restrict__ h2,
                       const unsigned short* __restrict__ h3,
                       const int* __restrict__ batch,
                       float* __restrict__ pooled) {
    __shared__ int sb[128];
    int col = threadIdx.x;            // 0..383
    int base = blockIdx.x * 128;
    if (col < 128) {
        int r = base + col;
        sb[col] = (r < N_NODES) ? batch[r] : -1;
    }
    __syncthreads();
    const unsigned short* h = (col < 128) ? h1 : (col < 256) ? h2 : h3;
    int c = col & 127;
    float acc = 0.f;
    int cur = -2;
    int lim = N_NODES - base;
    if (lim > 128) lim = 128;
    for (int r = 0; r < lim; ++r) {
        int g = sb[r];
        if (g != cur) {
            if (cur >= 0) atomicAdd(&pooled[cur * 384 + col], acc);
            acc = 0.f;
            cur = g;
        }
        acc += bf2f(h[(size_t)(base + r) * 128 + c]);
    }
    if (cur >= 0) atomicAdd(&pooled[cur * 384 + col], acc);
}

// ---------------- final: out = relu(pooled @ Wlin + blin) ----------------
__global__ void k_final(const float* __restrict__ pooled,
                        const float* __restrict__ Wlin,
                        const float* __restrict__ blin,
                        float* __restrict__ out) {
    int g = blockIdx.x, col = threadIdx.x;
    float acc = blin[col];
    for (int k = 0; k < 384; ++k)
        acc = fmaf(pooled[g * 384 + k], Wlin[k * 128 + col], acc);
    out[g * 128 + col] = acc > 0.f ? acc : 0.f;
}

extern "C" void kernel_launch(void* const* d_in, const int* in_sizes, int n_in,
                              void* d_out, int out_size, void* d_ws, size_t ws_size,
                              hipStream_t stream) {
    const float* x    = (const float*)d_in[0];
    const int*   ei   = (const int*)d_in[1];
    const int*   src  = ei;
    const int*   dst  = ei + N_EDGES;
    const int*   batch = (const int*)d_in[2];
    const float* W1l = (const float*)d_in[3];
    const float* b1  = (const float*)d_in[4];
    const float* W1r = (const float*)d_in[5];
    const float* W2l = (const float*)d_in[6];
    const float* b2  = (const float*)d_in[7];
    const float* W2r = (const float*)d_in[8];
    const float* W3l = (const float*)d_in[9];
    const float* b3  = (const float*)d_in[10];
    const float* W3r = (const float*)d_in[11];
    const float* Wlin = (const float*)d_in[12];
    const float* blin = (const float*)d_in[13];
    float* out = (float*)d_out;

    char* ws = (char*)d_ws;
    size_t off = 0;
    auto alloc = [&](size_t bytes) -> char* {
        char* p = ws + off;
        off = (off + bytes + 255) & ~(size_t)255;
        return p;
    };
    int* offsets = (int*)alloc((N_NODES + 1) * sizeof(int));
    int* cursor  = (int*)alloc(N_NODES * sizeof(int));
    int* deg     = (int*)alloc(N_NODES * sizeof(int));
    int* esrc    = (int*)alloc(N_EDGES * sizeof(int));
    unsigned short* h0   = (unsigned short*)alloc((size_t)N_NODES * 128 * 2);
    unsigned short* h1   = (unsigned short*)alloc((size_t)N_NODES * 128 * 2);
    unsigned short* h2   = (unsigned short*)alloc((size_t)N_NODES * 128 * 2);
    unsigned short* h3   = (unsigned short*)alloc((size_t)N_NODES * 128 * 2);
    unsigned short* aggb = (unsigned short*)alloc((size_t)N_NODES * 128 * 2);
    unsigned short* Wt   = (unsigned short*)alloc(3 * 256 * 128 * 2);
    float* pooled = (float*)alloc(NGRAPHS * 384 * sizeof(float));

    hipMemsetAsync(deg, 0, N_NODES * sizeof(int), stream);
    hipMemsetAsync(pooled, 0, NGRAPHS * 384 * sizeof(float), stream);

    k_count<<<(N_EDGES + 255) / 256, 256, 0, stream>>>(dst, deg);
    k_scan<<<1, 256, 0, stream>>>(deg, offsets, cursor);
    k_fill<<<(N_EDGES + 255) / 256, 256, 0, stream>>>(src, dst, cursor, esrc);
    k_castx<<<(N_NODES * 64 + 255) / 256, 256, 0, stream>>>(x, h0);
    k_castw<<<384, 256, 0, stream>>>(W1l, W1r, W2l, W2r, W3l, W3r, Wt);

    k_agg<<<N_NODES / 4, 256, 0, stream>>>(h0, offsets, esrc, aggb);
    k_gemm<<<625, 256, 0, stream>>>(aggb, h0, Wt, b1, h1);
    k_agg<<<N_NODES / 4, 256, 0, stream>>>(h1, offsets, esrc, aggb);
    k_gemm<<<625, 256, 0, stream>>>(aggb, h1, Wt + 32768, b2, h2);
    k_agg<<<N_NODES / 4, 256, 0, stream>>>(h2, offsets, esrc, aggb);
    k_gemm<<<625, 256, 0, stream>>>(aggb, h2, Wt + 2 * 32768, b3, h3);

    k_pool<<<(N_NODES + 127) / 128, 384, 0, stream>>>(h1, h2, h3, batch, pooled);
    k_final<<<NGRAPHS, 128, 0, stream>>>(pooled, Wlin, blin, out);
}

// Round 2
// 415.393 us; speedup vs baseline: 1.4478x; 1.4478x over previous
//
#include <hip/hip_runtime.h>
#include <hip/hip_bf16.h>

#define N_NODES 40000
#define N_EDGES 640000
#define NFEAT 128
#define NGRAPHS 64

typedef __attribute__((ext_vector_type(8))) short short8;
typedef __attribute__((ext_vector_type(4))) float float4v;

static __device__ __forceinline__ float bf2f(unsigned short u) {
    unsigned int x = ((unsigned int)u) << 16;
    return __builtin_bit_cast(float, x);
}
static __device__ __forceinline__ unsigned short f2bf(float f) {
    unsigned int x = __builtin_bit_cast(unsigned int, f);
    unsigned int r = x + 0x7fffu + ((x >> 16) & 1u);
    return (unsigned short)(r >> 16);
}

// ---------------- CSR build ----------------
__global__ void k_count(const int* __restrict__ dst, int* __restrict__ deg) {
    int e = blockIdx.x * 256 + threadIdx.x;
    if (e < N_EDGES) atomicAdd(&deg[dst[e]], 1);
}

// single block, 1024 threads; each thread owns a 40-element chunk
__global__ __launch_bounds__(1024) void k_scan(const int* __restrict__ deg,
                                               int* __restrict__ offsets,
                                               int* __restrict__ cursor) {
    __shared__ int wsum[16];
    int tid = threadIdx.x;
    const int PER = 40;                       // 1024*40 = 40960 >= 40000
    int start = tid * PER;
    int end = start + PER; if (end > N_NODES) end = N_NODES;
    int sum = 0;
    for (int i = start; i < end; ++i) sum += deg[i];
    int lane = tid & 63, wave = tid >> 6;
    int incl = sum;
    for (int d = 1; d < 64; d <<= 1) {
        int t = __shfl_up(incl, d, 64);
        if (lane >= d) incl += t;
    }
    if (lane == 63) wsum[wave] = incl;
    __syncthreads();
    if (wave == 0 && lane < 16) {
        int v = wsum[lane];
        for (int d = 1; d < 16; d <<= 1) {
            int t = __shfl_up(v, d, 64);
            if (lane >= d) v += t;
        }
        wsum[lane] = v;                       // inclusive wave prefix
    }
    __syncthreads();
    int waveOff = (wave == 0) ? 0 : wsum[wave - 1];
    int run = waveOff + incl - sum;           // exclusive prefix for this chunk
    for (int i = start; i < end; ++i) {
        int v = deg[i];
        offsets[i] = run;
        cursor[i]  = run;
        run += v;
    }
    if (tid == 0) offsets[N_NODES] = wsum[15];
}

__global__ void k_fill(const int* __restrict__ src, const int* __restrict__ dst,
                       int* __restrict__ cursor, int* __restrict__ esrc) {
    int e = blockIdx.x * 256 + threadIdx.x;
    if (e < N_EDGES) {
        int d = dst[e];
        int p = atomicAdd(&cursor[d], 1);
        esrc[p] = src[e];
    }
}

// ---------------- dtype prep ----------------
__global__ void k_castx(const float* __restrict__ x, unsigned short* __restrict__ h0) {
    int i = blockIdx.x * 256 + threadIdx.x;   // index over pairs
    const int n = N_NODES * NFEAT / 2;
    if (i < n) {
        float a = x[2 * i], b = x[2 * i + 1];
        unsigned int u = (unsigned int)f2bf(a) | ((unsigned int)f2bf(b) << 16);
        ((unsigned int*)h0)[i] = u;
    }
}

// Wt layout per layer: Wt[n][k] = Wcat[k][n], n in [0,128), k in [0,256)
__global__ void k_castw(const float* __restrict__ Wl0, const float* __restrict__ Wr0,
                        const float* __restrict__ Wl1, const float* __restrict__ Wr1,
                        const float* __restrict__ Wl2, const float* __restrict__ Wr2,
                        unsigned short* __restrict__ Wt) {
    int id = blockIdx.x * 256 + threadIdx.x;
    if (id >= 3 * 128 * 256) return;
    int l   = id >> 15;
    int rem = id & 32767;
    int nn  = rem >> 8;
    int k   = rem & 255;
    const float* Wl = (l == 0) ? Wl0 : (l == 1) ? Wl1 : Wl2;
    const float* Wr = (l == 0) ? Wr0 : (l == 1) ? Wr1 : Wr2;
    float v = (k < 128) ? Wl[k * 128 + nn] : Wr[(k - 128) * 128 + nn];
    Wt[id] = f2bf(v);
}

// ---------------- mean aggregation (one wave per node, 4 rows in flight) -----
__global__ void k_agg(const unsigned short* __restrict__ hin,
                      const int* __restrict__ offsets,
                      const int* __restrict__ esrc,
                      unsigned short* __restrict__ agg) {
    int wave = threadIdx.x >> 6;
    int lane = threadIdx.x & 63;
    int node = blockIdx.x * 4 + wave;
    if (node >= N_NODES) return;
    int beg = offsets[node], end = offsets[node + 1];
    int grp = lane >> 4;        // which neighbor row within a 4-row batch
    int sub = lane & 15;        // 16B column chunk
    float a[8];
    for (int i = 0; i < 8; ++i) a[i] = 0.f;
    for (int j = beg + grp; j < end; j += 4) {
        int s = esrc[j];
        uint4 u = *(const uint4*)(hin + (size_t)s * 128 + sub * 8);
        unsigned int w0 = u.x, w1 = u.y, w2 = u.z, w3 = u.w;
        a[0] += bf2f((unsigned short)(w0 & 0xffffu));
        a[1] += bf2f((unsigned short)(w0 >> 16));
        a[2] += bf2f((unsigned short)(w1 & 0xffffu));
        a[3] += bf2f((unsigned short)(w1 >> 16));
        a[4] += bf2f((unsigned short)(w2 & 0xffffu));
        a[5] += bf2f((unsigned short)(w2 >> 16));
        a[6] += bf2f((unsigned short)(w3 & 0xffffu));
        a[7] += bf2f((unsigned short)(w3 >> 16));
    }
    for (int i = 0; i < 8; ++i) {
        a[i] += __shfl_xor(a[i], 16, 64);
        a[i] += __shfl_xor(a[i], 32, 64);
    }
    int d = end - beg;
    float inv = 1.f / (float)(d > 1 ? d : 1);
    if (grp == 0) {
        uint4 v;
        v.x = (unsigned int)f2bf(a[0] * inv) | ((unsigned int)f2bf(a[1] * inv) << 16);
        v.y = (unsigned int)f2bf(a[2] * inv) | ((unsigned int)f2bf(a[3] * inv) << 16);
        v.z = (unsigned int)f2bf(a[4] * inv) | ((unsigned int)f2bf(a[5] * inv) << 16);
        v.w = (unsigned int)f2bf(a[6] * inv) | ((unsigned int)f2bf(a[7] * inv) << 16);
        *(uint4*)(agg + (size_t)node * 128 + sub * 8) = v;
    }
}

// ---------------- fused SAGE GEMM: hout = relu([agg|hin] @ [Wl;Wr] + b) ------
__global__ void k_gemm(const unsigned short* __restrict__ agg,
                       const unsigned short* __restrict__ hin,
                       const unsigned short* __restrict__ Wt,   // [128][256]
                       const float* __restrict__ bias,
                       unsigned short* __restrict__ hout) {
    __shared__ __align__(16) unsigned short As[64][264];
    int tid = threadIdx.x;
    int row0 = blockIdx.x * 64;

    {
        int c  = tid & 31;
        int r0 = tid >> 5;
        for (int p = 0; p < 8; ++p) {
            int r = r0 + p * 8;
            int grow = row0 + r;
            const unsigned short* srcp = (c < 16) ? (agg + (size_t)grow * 128 + c * 8)
                                                  : (hin + (size_t)grow * 128 + (c - 16) * 8);
            uint4 v = *(const uint4*)srcp;
            *(uint4*)(&As[r][c * 8]) = v;
        }
    }
    __syncthreads();

    int wave = tid >> 6, lane = tid & 63;
    int quad = lane >> 4, l16 = lane & 15;
    float4v acc[4][2];
    for (int rt = 0; rt < 4; ++rt)
        for (int ct = 0; ct < 2; ++ct) acc[rt][ct] = {0.f, 0.f, 0.f, 0.f};

    int ncol0 = wave * 32;
    for (int kc = 0; kc < 8; ++kc) {
        int k0 = kc * 32 + quad * 8;
        short8 a[4], b[2];
        for (int rt = 0; rt < 4; ++rt)
            a[rt] = *(const short8*)(&As[rt * 16 + l16][k0]);
        for (int ct = 0; ct < 2; ++ct)
            b[ct] = *(const short8*)(Wt + (size_t)(ncol0 + ct * 16 + l16) * 256 + k0);
        for (int rt = 0; rt < 4; ++rt)
            for (int ct = 0; ct < 2; ++ct)
                acc[rt][ct] = __builtin_amdgcn_mfma_f32_16x16x32_bf16(
                    a[rt], b[ct], acc[rt][ct], 0, 0, 0);
    }

    for (int ct = 0; ct < 2; ++ct) {
        int col = ncol0 + ct * 16 + l16;
        float bv = bias[col];
        for (int rt = 0; rt < 4; ++rt) {
            int r0 = rt * 16 + quad * 4;
            for (int i = 0; i < 4; ++i) {
                float v = acc[rt][ct][i] + bv;
                v = v > 0.f ? v : 0.f;
                hout[(size_t)(row0 + r0 + i) * 128 + col] = f2bf(v);
            }
        }
    }
}

// ---------------- pooling ----------------
__global__ void k_pool(const unsigned short* __restrict__ h1,
                       const unsigned short* __restrict__ h2,
                       const unsigned short* __restrict__ h3,
                       const int* __restrict__ batch,
                       float* __restrict__ pooled) {
    __shared__ int sb[128];
    int col = threadIdx.x;            // 0..383
    int base = blockIdx.x * 128;
    if (col < 128) {
        int r = base + col;
        sb[col] = (r < N_NODES) ? batch[r] : -1;
    }
    __syncthreads();
    const unsigned short* h = (col < 128) ? h1 : (col < 256) ? h2 : h3;
    int c = col & 127;
    float acc = 0.f;
    int cur = -2;
    int lim = N_NODES - base;
    if (lim > 128) lim = 128;
    for (int r = 0; r < lim; ++r) {
        int g = sb[r];
        if (g != cur) {
            if (cur >= 0) atomicAdd(&pooled[cur * 384 + col], acc);
            acc = 0.f;
            cur = g;
        }
        acc += bf2f(h[(size_t)(base + r) * 128 + c]);
    }
    if (cur >= 0) atomicAdd(&pooled[cur * 384 + col], acc);
}

// ---------------- final ----------------
__global__ void k_final(const float* __restrict__ pooled,
                        const float* __restrict__ Wlin,
                        const float* __restrict__ blin,
                        float* __restrict__ out) {
    int g = blockIdx.x, col = threadIdx.x;
    float acc = blin[col];
    for (int k = 0; k < 384; ++k)
        acc = fmaf(pooled[g * 384 + k], Wlin[k * 128 + col], acc);
    out[g * 128 + col] = acc > 0.f ? acc : 0.f;
}

extern "C" void kernel_launch(void* const* d_in, const int* in_sizes, int n_in,
                              void* d_out, int out_size, void* d_ws, size_t ws_size,
                              hipStream_t stream) {
    const float* x    = (const float*)d_in[0];
    const int*   ei   = (const int*)d_in[1];
    const int*   src  = ei;
    const int*   dst  = ei + N_EDGES;
    const int*   batch = (const int*)d_in[2];
    const float* W1l = (const float*)d_in[3];
    const float* b1  = (const float*)d_in[4];
    const float* W1r = (const float*)d_in[5];
    const float* W2l = (const float*)d_in[6];
    const float* b2  = (const float*)d_in[7];
    const float* W2r = (const float*)d_in[8];
    const float* W3l = (const float*)d_in[9];
    const float* b3  = (const float*)d_in[10];
    const float* W3r = (const float*)d_in[11];
    const float* Wlin = (const float*)d_in[12];
    const float* blin = (const float*)d_in[13];
    float* out = (float*)d_out;

    char* ws = (char*)d_ws;
    size_t off = 0;
    auto alloc = [&](size_t bytes) -> char* {
        char* p = ws + off;
        off = (off + bytes + 255) & ~(size_t)255;
        return p;
    };
    int* offsets = (int*)alloc((N_NODES + 1) * sizeof(int));
    int* cursor  = (int*)alloc(N_NODES * sizeof(int));
    int* deg     = (int*)alloc(N_NODES * sizeof(int));
    int* esrc    = (int*)alloc(N_EDGES * sizeof(int));
    unsigned short* h0   = (unsigned short*)alloc((size_t)N_NODES * 128 * 2);
    unsigned short* h1   = (unsigned short*)alloc((size_t)N_NODES * 128 * 2);
    unsigned short* h2   = (unsigned short*)alloc((size_t)N_NODES * 128 * 2);
    unsigned short* h3   = (unsigned short*)alloc((size_t)N_NODES * 128 * 2);
    unsigned short* aggb = (unsigned short*)alloc((size_t)N_NODES * 128 * 2);
    unsigned short* Wt   = (unsigned short*)alloc(3 * 256 * 128 * 2);
    float* pooled = (float*)alloc(NGRAPHS * 384 * sizeof(float));

    hipMemsetAsync(deg, 0, N_NODES * sizeof(int), stream);
    hipMemsetAsync(pooled, 0, NGRAPHS * 384 * sizeof(float), stream);

    k_count<<<(N_EDGES + 255) / 256, 256, 0, stream>>>(dst, deg);
    k_scan<<<1, 1024, 0, stream>>>(deg, offsets, cursor);
    k_fill<<<(N_EDGES + 255) / 256, 256, 0, stream>>>(src, dst, cursor, esrc);
    k_castx<<<(N_NODES * 64 + 255) / 256, 256, 0, stream>>>(x, h0);
    k_castw<<<384, 256, 0, stream>>>(W1l, W1r, W2l, W2r, W3l, W3r, Wt);

    k_agg<<<N_NODES / 4, 256, 0, stream>>>(h0, offsets, esrc, aggb);
    k_gemm<<<625, 256, 0, stream>>>(aggb, h0, Wt, b1, h1);
    k_agg<<<N_NODES / 4, 256, 0, stream>>>(h1, offsets, esrc, aggb);
    k_gemm<<<625, 256, 0, stream>>>(aggb, h1, Wt + 32768, b2, h2);
    k_agg<<<N_NODES / 4, 256, 0, stream>>>(h2, offsets, esrc, aggb);
    k_gemm<<<625, 256, 0, stream>>>(aggb, h2, Wt + 2 * 32768, b3, h3);

    k_pool<<<(N_NODES + 127) / 128, 384, 0, stream>>>(h1, h2, h3, batch, pooled);
    k_final<<<NGRAPHS, 128, 0, stream>>>(pooled, Wlin, blin, out);
}

// Round 3
// 331.108 us; speedup vs baseline: 1.8163x; 1.2546x over previous
//
#include <hip/hip_runtime.h>
#include <hip/hip_bf16.h>

#define N_NODES 40000
#define N_EDGES 640000
#define NFEAT 128
#define NGRAPHS 64

typedef __attribute__((ext_vector_type(8))) short short8;
typedef __attribute__((ext_vector_type(4))) float float4v;

static __device__ __forceinline__ float bf2f(unsigned short u) {
    unsigned int x = ((unsigned int)u) << 16;
    return __builtin_bit_cast(float, x);
}
static __device__ __forceinline__ unsigned short f2bf(float f) {
    unsigned int x = __builtin_bit_cast(unsigned int, f);
    unsigned int r = x + 0x7fffu + ((x >> 16) & 1u);
    return (unsigned short)(r >> 16);
}

// ---------------- CSR build ----------------
__global__ void k_count(const int* __restrict__ dst, int* __restrict__ deg) {
    int e = blockIdx.x * 256 + threadIdx.x;
    if (e < N_EDGES) atomicAdd(&deg[dst[e]], 1);
}

// Pass 1: 40 blocks x 1024 threads, coalesced block scan.
// Writes block-local EXCLUSIVE prefix into offsets[], block totals into bsum[].
__global__ __launch_bounds__(1024) void k_scan1(const int* __restrict__ deg,
                                                int* __restrict__ offsets,
                                                int* __restrict__ bsum) {
    __shared__ int ws[16];
    int tid = threadIdx.x;
    int i = blockIdx.x * 1024 + tid;
    int v = (i < N_NODES) ? deg[i] : 0;
    int lane = tid & 63, wave = tid >> 6;
    int incl = v;
    for (int d = 1; d < 64; d <<= 1) {
        int t = __shfl_up(incl, d, 64);
        if (lane >= d) incl += t;
    }
    if (lane == 63) ws[wave] = incl;
    __syncthreads();
    if (wave == 0 && lane < 16) {
        int w = ws[lane];
        for (int d = 1; d < 16; d <<= 1) {
            int t = __shfl_up(w, d, 64);
            if (lane >= d) w += t;
        }
        ws[lane] = w;
    }
    __syncthreads();
    int waveOff = (wave == 0) ? 0 : ws[wave - 1];
    if (i < N_NODES) offsets[i] = waveOff + incl - v;   // block-local exclusive
    if (tid == 1023) bsum[blockIdx.x] = ws[15];
}

// Pass 2: 40 blocks; each block adds its block offset (scan of bsum) and
// writes final offsets + cursor. offsets[N_NODES] = N_EDGES (hardcoded).
__global__ __launch_bounds__(1024) void k_scan3(const int* __restrict__ bsum,
                                                int* __restrict__ offsets,
                                                int* __restrict__ cursor) {
    __shared__ int s_boff;
    int tid = threadIdx.x;
    if (tid < 64) {
        int v = (tid < 40) ? bsum[tid] : 0;
        int incl = v;
        for (int d = 1; d < 64; d <<= 1) {
            int t = __shfl_up(incl, d, 64);
            if (tid >= d) incl += t;
        }
        int excl = incl - v;
        int my = __shfl(excl, blockIdx.x, 64);
        if (tid == 0) s_boff = my;
    }
    __syncthreads();
    int boff = s_boff;
    int i = blockIdx.x * 1024 + tid;
    if (i < N_NODES) {
        int o = offsets[i] + boff;
        offsets[i] = o;
        cursor[i]  = o;
    }
    if (blockIdx.x == 0 && tid == 0) offsets[N_NODES] = N_EDGES;
}

__global__ void k_fill(const int* __restrict__ src, const int* __restrict__ dst,
                       int* __restrict__ cursor, int* __restrict__ esrc) {
    int e = blockIdx.x * 256 + threadIdx.x;
    if (e < N_EDGES) {
        int d = dst[e];
        int p = atomicAdd(&cursor[d], 1);
        esrc[p] = src[e];
    }
}

// ---------------- dtype prep ----------------
__global__ void k_castx(const float* __restrict__ x, unsigned short* __restrict__ h0) {
    int i = blockIdx.x * 256 + threadIdx.x;   // index over pairs
    const int n = N_NODES * NFEAT / 2;
    if (i < n) {
        float a = x[2 * i], b = x[2 * i + 1];
        unsigned int u = (unsigned int)f2bf(a) | ((unsigned int)f2bf(b) << 16);
        ((unsigned int*)h0)[i] = u;
    }
}

// Wt layout per layer: Wt[n][k] = Wcat[k][n], n in [0,128), k in [0,256)
__global__ void k_castw(const float* __restrict__ Wl0, const float* __restrict__ Wr0,
                        const float* __restrict__ Wl1, const float* __restrict__ Wr1,
                        const float* __restrict__ Wl2, const float* __restrict__ Wr2,
                        unsigned short* __restrict__ Wt) {
    int id = blockIdx.x * 256 + threadIdx.x;
    if (id >= 3 * 128 * 256) return;
    int l   = id >> 15;
    int rem = id & 32767;
    int nn  = rem >> 8;
    int k   = rem & 255;
    const float* Wl = (l == 0) ? Wl0 : (l == 1) ? Wl1 : Wl2;
    const float* Wr = (l == 0) ? Wr0 : (l == 1) ? Wr1 : Wr2;
    float v = (k < 128) ? Wl[k * 128 + nn] : Wr[(k - 128) * 128 + nn];
    Wt[id] = f2bf(v);
}

// ---------------- mean aggregation (one wave per node, 4 rows in flight) -----
__global__ void k_agg(const unsigned short* __restrict__ hin,
                      const int* __restrict__ offsets,
                      const int* __restrict__ esrc,
                      unsigned short* __restrict__ agg) {
    int wave = threadIdx.x >> 6;
    int lane = threadIdx.x & 63;
    int node = blockIdx.x * 4 + wave;
    if (node >= N_NODES) return;
    int beg = offsets[node], end = offsets[node + 1];
    int grp = lane >> 4;        // which neighbor row within a 4-row batch
    int sub = lane & 15;        // 16B column chunk
    float a[8];
    for (int i = 0; i < 8; ++i) a[i] = 0.f;
    for (int j = beg + grp; j < end; j += 4) {
        int s = esrc[j];
        uint4 u = *(const uint4*)(hin + (size_t)s * 128 + sub * 8);
        unsigned int w0 = u.x, w1 = u.y, w2 = u.z, w3 = u.w;
        a[0] += bf2f((unsigned short)(w0 & 0xffffu));
        a[1] += bf2f((unsigned short)(w0 >> 16));
        a[2] += bf2f((unsigned short)(w1 & 0xffffu));
        a[3] += bf2f((unsigned short)(w1 >> 16));
        a[4] += bf2f((unsigned short)(w2 & 0xffffu));
        a[5] += bf2f((unsigned short)(w2 >> 16));
        a[6] += bf2f((unsigned short)(w3 & 0xffffu));
        a[7] += bf2f((unsigned short)(w3 >> 16));
    }
    for (int i = 0; i < 8; ++i) {
        a[i] += __shfl_xor(a[i], 16, 64);
        a[i] += __shfl_xor(a[i], 32, 64);
    }
    int d = end - beg;
    float inv = 1.f / (float)(d > 1 ? d : 1);
    if (grp == 0) {
        uint4 v;
        v.x = (unsigned int)f2bf(a[0] * inv) | ((unsigned int)f2bf(a[1] * inv) << 16);
        v.y = (unsigned int)f2bf(a[2] * inv) | ((unsigned int)f2bf(a[3] * inv) << 16);
        v.z = (unsigned int)f2bf(a[4] * inv) | ((unsigned int)f2bf(a[5] * inv) << 16);
        v.w = (unsigned int)f2bf(a[6] * inv) | ((unsigned int)f2bf(a[7] * inv) << 16);
        *(uint4*)(agg + (size_t)node * 128 + sub * 8) = v;
    }
}

// ---------------- fused SAGE GEMM: hout = relu([agg|hin] @ [Wl;Wr] + b) ------
__global__ void k_gemm(const unsigned short* __restrict__ agg,
                       const unsigned short* __restrict__ hin,
                       const unsigned short* __restrict__ Wt,   // [128][256]
                       const float* __restrict__ bias,
                       unsigned short* __restrict__ hout) {
    __shared__ __align__(16) unsigned short As[64][264];
    int tid = threadIdx.x;
    int row0 = blockIdx.x * 64;

    {
        int c  = tid & 31;
        int r0 = tid >> 5;
        for (int p = 0; p < 8; ++p) {
            int r = r0 + p * 8;
            int grow = row0 + r;
            const unsigned short* srcp = (c < 16) ? (agg + (size_t)grow * 128 + c * 8)
                                                  : (hin + (size_t)grow * 128 + (c - 16) * 8);
            uint4 v = *(const uint4*)srcp;
            *(uint4*)(&As[r][c * 8]) = v;
        }
    }
    __syncthreads();

    int wave = tid >> 6, lane = tid & 63;
    int quad = lane >> 4, l16 = lane & 15;
    float4v acc[4][2];
    for (int rt = 0; rt < 4; ++rt)
        for (int ct = 0; ct < 2; ++ct) acc[rt][ct] = {0.f, 0.f, 0.f, 0.f};

    int ncol0 = wave * 32;
    for (int kc = 0; kc < 8; ++kc) {
        int k0 = kc * 32 + quad * 8;
        short8 a[4], b[2];
        for (int rt = 0; rt < 4; ++rt)
            a[rt] = *(const short8*)(&As[rt * 16 + l16][k0]);
        for (int ct = 0; ct < 2; ++ct)
            b[ct] = *(const short8*)(Wt + (size_t)(ncol0 + ct * 16 + l16) * 256 + k0);
        for (int rt = 0; rt < 4; ++rt)
            for (int ct = 0; ct < 2; ++ct)
                acc[rt][ct] = __builtin_amdgcn_mfma_f32_16x16x32_bf16(
                    a[rt], b[ct], acc[rt][ct], 0, 0, 0);
    }

    for (int ct = 0; ct < 2; ++ct) {
        int col = ncol0 + ct * 16 + l16;
        float bv = bias[col];
        for (int rt = 0; rt < 4; ++rt) {
            int r0 = rt * 16 + quad * 4;
            for (int i = 0; i < 4; ++i) {
                float v = acc[rt][ct][i] + bv;
                v = v > 0.f ? v : 0.f;
                hout[(size_t)(row0 + r0 + i) * 128 + col] = f2bf(v);
            }
        }
    }
}

// ---------------- pooling ----------------
__global__ void k_pool(const unsigned short* __restrict__ h1,
                       const unsigned short* __restrict__ h2,
                       const unsigned short* __restrict__ h3,
                       const int* __restrict__ batch,
                       float* __restrict__ pooled) {
    __shared__ int sb[128];
    int col = threadIdx.x;            // 0..383
    int base = blockIdx.x * 128;
    if (col < 128) {
        int r = base + col;
        sb[col] = (r < N_NODES) ? batch[r] : -1;
    }
    __syncthreads();
    const unsigned short* h = (col < 128) ? h1 : (col < 256) ? h2 : h3;
    int c = col & 127;
    float acc = 0.f;
    int cur = -2;
    int lim = N_NODES - base;
    if (lim > 128) lim = 128;
    for (int r = 0; r < lim; ++r) {
        int g = sb[r];
        if (g != cur) {
            if (cur >= 0) atomicAdd(&pooled[cur * 384 + col], acc);
            acc = 0.f;
            cur = g;
        }
        acc += bf2f(h[(size_t)(base + r) * 128 + c]);
    }
    if (cur >= 0) atomicAdd(&pooled[cur * 384 + col], acc);
}

// ---------------- final ----------------
__global__ void k_final(const float* __restrict__ pooled,
                        const float* __restrict__ Wlin,
                        const float* __restrict__ blin,
                        float* __restrict__ out) {
    int g = blockIdx.x, col = threadIdx.x;
    float acc = blin[col];
    for (int k = 0; k < 384; ++k)
        acc = fmaf(pooled[g * 384 + k], Wlin[k * 128 + col], acc);
    out[g * 128 + col] = acc > 0.f ? acc : 0.f;
}

extern "C" void kernel_launch(void* const* d_in, const int* in_sizes, int n_in,
                              void* d_out, int out_size, void* d_ws, size_t ws_size,
                              hipStream_t stream) {
    const float* x    = (const float*)d_in[0];
    const int*   ei   = (const int*)d_in[1];
    const int*   src  = ei;
    const int*   dst  = ei + N_EDGES;
    const int*   batch = (const int*)d_in[2];
    const float* W1l = (const float*)d_in[3];
    const float* b1  = (const float*)d_in[4];
    const float* W1r = (const float*)d_in[5];
    const float* W2l = (const float*)d_in[6];
    const float* b2  = (const float*)d_in[7];
    const float* W2r = (const float*)d_in[8];
    const float* W3l = (const float*)d_in[9];
    const float* b3  = (const float*)d_in[10];
    const float* W3r = (const float*)d_in[11];
    const float* Wlin = (const float*)d_in[12];
    const float* blin = (const float*)d_in[13];
    float* out = (float*)d_out;

    char* ws = (char*)d_ws;
    size_t off = 0;
    auto alloc = [&](size_t bytes) -> char* {
        char* p = ws + off;
        off = (off + bytes + 255) & ~(size_t)255;
        return p;
    };
    int* offsets = (int*)alloc((N_NODES + 1) * sizeof(int));
    int* cursor  = (int*)alloc(N_NODES * sizeof(int));
    int* deg     = (int*)alloc(N_NODES * sizeof(int));
    int* bsum    = (int*)alloc(64 * sizeof(int));
    int* esrc    = (int*)alloc(N_EDGES * sizeof(int));
    unsigned short* h0   = (unsigned short*)alloc((size_t)N_NODES * 128 * 2);
    unsigned short* h1   = (unsigned short*)alloc((size_t)N_NODES * 128 * 2);
    unsigned short* h2   = (unsigned short*)alloc((size_t)N_NODES * 128 * 2);
    unsigned short* h3   = (unsigned short*)alloc((size_t)N_NODES * 128 * 2);
    unsigned short* aggb = (unsigned short*)alloc((size_t)N_NODES * 128 * 2);
    unsigned short* Wt   = (unsigned short*)alloc(3 * 256 * 128 * 2);
    float* pooled = (float*)alloc(NGRAPHS * 384 * sizeof(float));

    hipMemsetAsync(deg, 0, N_NODES * sizeof(int), stream);
    hipMemsetAsync(pooled, 0, NGRAPHS * 384 * sizeof(float), stream);

    k_count<<<(N_EDGES + 255) / 256, 256, 0, stream>>>(dst, deg);
    k_scan1<<<40, 1024, 0, stream>>>(deg, offsets, bsum);
    k_scan3<<<40, 1024, 0, stream>>>(bsum, offsets, cursor);
    k_fill<<<(N_EDGES + 255) / 256, 256, 0, stream>>>(src, dst, cursor, esrc);
    k_castx<<<(N_NODES * 64 + 255) / 256, 256, 0, stream>>>(x, h0);
    k_castw<<<384, 256, 0, stream>>>(W1l, W1r, W2l, W2r, W3l, W3r, Wt);

    k_agg<<<N_NODES / 4, 256, 0, stream>>>(h0, offsets, esrc, aggb);
    k_gemm<<<625, 256, 0, stream>>>(aggb, h0, Wt, b1, h1);
    k_agg<<<N_NODES / 4, 256, 0, stream>>>(h1, offsets, esrc, aggb);
    k_gemm<<<625, 256, 0, stream>>>(aggb, h1, Wt + 32768, b2, h2);
    k_agg<<<N_NODES / 4, 256, 0, stream>>>(h2, offsets, esrc, aggb);
    k_gemm<<<625, 256, 0, stream>>>(aggb, h2, Wt + 2 * 32768, b3, h3);

    k_pool<<<(N_NODES + 127) / 128, 384, 0, stream>>>(h1, h2, h3, batch, pooled);
    k_final<<<NGRAPHS, 128, 0, stream>>>(pooled, Wlin, blin, out);
}

// Round 5
// 288.311 us; speedup vs baseline: 2.0859x; 1.1484x over previous
//
#include <hip/hip_runtime.h>
#include <hip/hip_bf16.h>

#define N_NODES 40000
#define N_EDGES 640000
#define NFEAT 128
#define NGRAPHS 64

typedef __attribute__((ext_vector_type(8))) short short8;
typedef __attribute__((ext_vector_type(4))) float float4v;

static __device__ __forceinline__ float bf2f(unsigned short u) {
    unsigned int x = ((unsigned int)u) << 16;
    return __builtin_bit_cast(float, x);
}
static __device__ __forceinline__ unsigned short f2bf(float f) {
    unsigned int x = __builtin_bit_cast(unsigned int, f);
    unsigned int r = x + 0x7fffu + ((x >> 16) & 1u);
    return (unsigned short)(r >> 16);
}

// ---------------- CSR build ----------------
__global__ void k_count(const int* __restrict__ dst, int* __restrict__ deg) {
    int e = blockIdx.x * 256 + threadIdx.x;
    if (e < N_EDGES) atomicAdd(&deg[dst[e]], 1);
}

__global__ __launch_bounds__(1024) void k_scan1(const int* __restrict__ deg,
                                                int* __restrict__ offsets,
                                                int* __restrict__ bsum) {
    __shared__ int ws[16];
    int tid = threadIdx.x;
    int i = blockIdx.x * 1024 + tid;
    int v = (i < N_NODES) ? deg[i] : 0;
    int lane = tid & 63, wave = tid >> 6;
    int incl = v;
    for (int d = 1; d < 64; d <<= 1) {
        int t = __shfl_up(incl, d, 64);
        if (lane >= d) incl += t;
    }
    if (lane == 63) ws[wave] = incl;
    __syncthreads();
    if (wave == 0 && lane < 16) {
        int w = ws[lane];
        for (int d = 1; d < 16; d <<= 1) {
            int t = __shfl_up(w, d, 64);
            if (lane >= d) w += t;
        }
        ws[lane] = w;
    }
    __syncthreads();
    int waveOff = (wave == 0) ? 0 : ws[wave - 1];
    if (i < N_NODES) offsets[i] = waveOff + incl - v;
    if (tid == 1023) bsum[blockIdx.x] = ws[15];
}

__global__ __launch_bounds__(1024) void k_scan3(const int* __restrict__ bsum,
                                                int* __restrict__ offsets,
                                                int* __restrict__ cursor) {
    __shared__ int s_boff;
    int tid = threadIdx.x;
    if (tid < 64) {
        int v = (tid < 40) ? bsum[tid] : 0;
        int incl = v;
        for (int d = 1; d < 64; d <<= 1) {
            int t = __shfl_up(incl, d, 64);
            if (tid >= d) incl += t;
        }
        int excl = incl - v;
        int my = __shfl(excl, blockIdx.x, 64);
        if (tid == 0) s_boff = my;
    }
    __syncthreads();
    int boff = s_boff;
    int i = blockIdx.x * 1024 + tid;
    if (i < N_NODES) {
        int o = offsets[i] + boff;
        offsets[i] = o;
        cursor[i]  = o;
    }
    if (blockIdx.x == 0 && tid == 0) offsets[N_NODES] = N_EDGES;
}

__global__ void k_fill(const int* __restrict__ src, const int* __restrict__ dst,
                       int* __restrict__ cursor, int* __restrict__ esrc) {
    int e = blockIdx.x * 256 + threadIdx.x;
    if (e < N_EDGES) {
        int d = dst[e];
        int p = atomicAdd(&cursor[d], 1);
        esrc[p] = src[e];
    }
}

// graph row ranges from sorted batch
__global__ void k_goff(const int* __restrict__ batch, int* __restrict__ goff) {
    int i = blockIdx.x * 256 + threadIdx.x;
    if (i >= N_NODES) return;
    int b1 = batch[i];
    int b0 = (i == 0) ? -1 : batch[i - 1];
    for (int g = b0 + 1; g <= b1; ++g) goff[g] = i;
    if (i == N_NODES - 1)
        for (int g = b1 + 1; g <= NGRAPHS; ++g) goff[g] = N_NODES;
}

// ---------------- dtype prep ----------------
__global__ void k_castx(const float* __restrict__ x, unsigned short* __restrict__ h0) {
    int i = blockIdx.x * 256 + threadIdx.x;
    const int n = N_NODES * NFEAT / 2;
    if (i < n) {
        float a = x[2 * i], b = x[2 * i + 1];
        unsigned int u = (unsigned int)f2bf(a) | ((unsigned int)f2bf(b) << 16);
        ((unsigned int*)h0)[i] = u;
    }
}

__global__ void k_castw(const float* __restrict__ Wl0, const float* __restrict__ Wr0,
                        const float* __restrict__ Wl1, const float* __restrict__ Wr1,
                        const float* __restrict__ Wl2, const float* __restrict__ Wr2,
                        unsigned short* __restrict__ Wt) {
    int id = blockIdx.x * 256 + threadIdx.x;
    if (id >= 3 * 128 * 256) return;
    int l   = id >> 15;
    int rem = id & 32767;
    int nn  = rem >> 8;
    int k   = rem & 255;
    const float* Wl = (l == 0) ? Wl0 : (l == 1) ? Wl1 : Wl2;
    const float* Wr = (l == 0) ? Wr0 : (l == 1) ? Wr1 : Wr2;
    float v = (k < 128) ? Wl[k * 128 + nn] : Wr[(k - 128) * 128 + nn];
    Wt[id] = f2bf(v);
}

// ---------------- mean aggregation ----------------
// one wave per node. Neighbor indices preloaded coalesced into sj (lane j holds
// neighbor j). ALL __shfl broadcasts execute at full exec: main loop has a
// wave-uniform trip count (nb is wave-uniform), remainder hoists the shfl
// before the predicated load. (Shfl under divergent exec reads inactive lanes
// -> garbage; that was R4's correctness bug.)
__global__ void k_agg(const unsigned short* __restrict__ hin,
                      const int* __restrict__ offsets,
                      const int* __restrict__ esrc,
                      unsigned short* __restrict__ agg) {
    int wave = threadIdx.x >> 6;
    int lane = threadIdx.x & 63;
    int node = blockIdx.x * 4 + wave;
    if (node >= N_NODES) return;
    int beg = offsets[node], end = offsets[node + 1];
    int deg = end - beg;
    int grp = lane >> 4;
    int sub = lane & 15;
    int nb = deg < 64 ? deg : 64;
    int sj = (lane < nb) ? esrc[beg + lane] : 0;

    float a[8];
    for (int i = 0; i < 8; ++i) a[i] = 0.f;
    auto acc8 = [&](uint4 u) {
        a[0] += bf2f((unsigned short)(u.x & 0xffffu));
        a[1] += bf2f((unsigned short)(u.x >> 16));
        a[2] += bf2f((unsigned short)(u.y & 0xffffu));
        a[3] += bf2f((unsigned short)(u.y >> 16));
        a[4] += bf2f((unsigned short)(u.z & 0xffffu));
        a[5] += bf2f((unsigned short)(u.z >> 16));
        a[6] += bf2f((unsigned short)(u.w & 0xffffu));
        a[7] += bf2f((unsigned short)(u.w >> 16));
    };

    // main loop: uniform trip count, both broadcasts at full exec
    int base = 0;
    for (; base + 8 <= nb; base += 8) {
        int s0 = __shfl(sj, base + grp, 64);
        int s1 = __shfl(sj, base + grp + 4, 64);
        uint4 u0 = *(const uint4*)(hin + (size_t)s0 * 128 + sub * 8);
        uint4 u1 = *(const uint4*)(hin + (size_t)s1 * 128 + sub * 8);
        acc8(u0);
        acc8(u1);
    }
    // remainder (< 8 elems): shfl at full exec, load predicated per group
    {
        int j0 = base + grp;
        int j1 = base + grp + 4;
        int s0 = __shfl(sj, j0 & 63, 64);
        int s1 = __shfl(sj, j1 & 63, 64);
        if (j0 < nb) {
            uint4 u = *(const uint4*)(hin + (size_t)s0 * 128 + sub * 8);
            acc8(u);
        }
        if (j1 < nb) {
            uint4 u = *(const uint4*)(hin + (size_t)s1 * 128 + sub * 8);
            acc8(u);
        }
    }
    // rare tail (deg > 64): direct index loads, no shfl
    for (int t = beg + 64 + grp; t < end; t += 4) {
        int s = esrc[t];
        uint4 u = *(const uint4*)(hin + (size_t)s * 128 + sub * 8);
        acc8(u);
    }

    for (int i = 0; i < 8; ++i) {
        a[i] += __shfl_xor(a[i], 16, 64);
        a[i] += __shfl_xor(a[i], 32, 64);
    }
    float inv = 1.f / (float)(deg > 1 ? deg : 1);
    if (grp == 0) {
        uint4 v;
        v.x = (unsigned int)f2bf(a[0] * inv) | ((unsigned int)f2bf(a[1] * inv) << 16);
        v.y = (unsigned int)f2bf(a[2] * inv) | ((unsigned int)f2bf(a[3] * inv) << 16);
        v.z = (unsigned int)f2bf(a[4] * inv) | ((unsigned int)f2bf(a[5] * inv) << 16);
        v.w = (unsigned int)f2bf(a[6] * inv) | ((unsigned int)f2bf(a[7] * inv) << 16);
        *(uint4*)(agg + (size_t)node * 128 + sub * 8) = v;
    }
}

// ---------------- fused SAGE GEMM ----------------
__global__ void k_gemm(const unsigned short* __restrict__ agg,
                       const unsigned short* __restrict__ hin,
                       const unsigned short* __restrict__ Wt,
                       const float* __restrict__ bias,
                       unsigned short* __restrict__ hout) {
    __shared__ __align__(16) unsigned short As[64][264];
    int tid = threadIdx.x;
    int row0 = blockIdx.x * 64;

    {
        int c  = tid & 31;
        int r0 = tid >> 5;
        for (int p = 0; p < 8; ++p) {
            int r = r0 + p * 8;
            int grow = row0 + r;
            const unsigned short* srcp = (c < 16) ? (agg + (size_t)grow * 128 + c * 8)
                                                  : (hin + (size_t)grow * 128 + (c - 16) * 8);
            uint4 v = *(const uint4*)srcp;
            *(uint4*)(&As[r][c * 8]) = v;
        }
    }
    __syncthreads();

    int wave = tid >> 6, lane = tid & 63;
    int quad = lane >> 4, l16 = lane & 15;
    float4v acc[4][2];
    for (int rt = 0; rt < 4; ++rt)
        for (int ct = 0; ct < 2; ++ct) acc[rt][ct] = {0.f, 0.f, 0.f, 0.f};

    int ncol0 = wave * 32;
    for (int kc = 0; kc < 8; ++kc) {
        int k0 = kc * 32 + quad * 8;
        short8 a[4], b[2];
        for (int rt = 0; rt < 4; ++rt)
            a[rt] = *(const short8*)(&As[rt * 16 + l16][k0]);
        for (int ct = 0; ct < 2; ++ct)
            b[ct] = *(const short8*)(Wt + (size_t)(ncol0 + ct * 16 + l16) * 256 + k0);
        for (int rt = 0; rt < 4; ++rt)
            for (int ct = 0; ct < 2; ++ct)
                acc[rt][ct] = __builtin_amdgcn_mfma_f32_16x16x32_bf16(
                    a[rt], b[ct], acc[rt][ct], 0, 0, 0);
    }

    for (int ct = 0; ct < 2; ++ct) {
        int col = ncol0 + ct * 16 + l16;
        float bv = bias[col];
        for (int rt = 0; rt < 4; ++rt) {
            int r0 = rt * 16 + quad * 4;
            for (int i = 0; i < 4; ++i) {
                float v = acc[rt][ct][i] + bv;
                v = v > 0.f ? v : 0.f;
                hout[(size_t)(row0 + r0 + i) * 128 + col] = f2bf(v);
            }
        }
    }
}

// ---------------- pooling: one block per (graph, layer), no atomics ---------
__global__ __launch_bounds__(256) void k_pool(const unsigned short* __restrict__ h1,
                                              const unsigned short* __restrict__ h2,
                                              const unsigned short* __restrict__ h3,
                                              const int* __restrict__ goff,
                                              float* __restrict__ pooled) {
    __shared__ float red[4][16][8];
    int b = blockIdx.x;
    int g = b / 3, aidx = b % 3;
    const unsigned short* h = (aidx == 0) ? h1 : (aidx == 1) ? h2 : h3;
    int beg = goff[g], end = goff[g + 1];
    int tid = threadIdx.x;
    int rp = tid >> 4;          // 0..15 rows in flight
    int ch = tid & 15;          // 16B column chunk
    float a[8];
    for (int i = 0; i < 8; ++i) a[i] = 0.f;
    for (int r = beg + rp; r < end; r += 16) {
        uint4 u = *(const uint4*)(h + (size_t)r * 128 + ch * 8);
        a[0] += bf2f((unsigned short)(u.x & 0xffffu));
        a[1] += bf2f((unsigned short)(u.x >> 16));
        a[2] += bf2f((unsigned short)(u.y & 0xffffu));
        a[3] += bf2f((unsigned short)(u.y >> 16));
        a[4] += bf2f((unsigned short)(u.z & 0xffffu));
        a[5] += bf2f((unsigned short)(u.z >> 16));
        a[6] += bf2f((unsigned short)(u.w & 0xffffu));
        a[7] += bf2f((unsigned short)(u.w >> 16));
    }
    for (int i = 0; i < 8; ++i) {
        a[i] += __shfl_xor(a[i], 16, 64);
        a[i] += __shfl_xor(a[i], 32, 64);
    }
    int wave = tid >> 6, lane = tid & 63;
    if (lane < 16)
        for (int i = 0; i < 8; ++i) red[wave][lane][i] = a[i];
    __syncthreads();
    if (tid < 128) {
        int ch2 = tid >> 3, e = tid & 7;
        float s = red[0][ch2][e] + red[1][ch2][e] + red[2][ch2][e] + red[3][ch2][e];
        pooled[g * 384 + aidx * 128 + ch2 * 8 + e] = s;
    }
}

// ---------------- final ----------------
__global__ void k_final(const float* __restrict__ pooled,
                        const float* __restrict__ Wlin,
                        const float* __restrict__ blin,
                        float* __restrict__ out) {
    int g = blockIdx.x, col = threadIdx.x;
    float acc = blin[col];
    for (int k = 0; k < 384; ++k)
        acc = fmaf(pooled[g * 384 + k], Wlin[k * 128 + col], acc);
    out[g * 128 + col] = acc > 0.f ? acc : 0.f;
}

extern "C" void kernel_launch(void* const* d_in, const int* in_sizes, int n_in,
                              void* d_out, int out_size, void* d_ws, size_t ws_size,
                              hipStream_t stream) {
    const float* x    = (const float*)d_in[0];
    const int*   ei   = (const int*)d_in[1];
    const int*   src  = ei;
    const int*   dst  = ei + N_EDGES;
    const int*   batch = (const int*)d_in[2];
    const float* W1l = (const float*)d_in[3];
    const float* b1  = (const float*)d_in[4];
    const float* W1r = (const float*)d_in[5];
    const float* W2l = (const float*)d_in[6];
    const float* b2  = (const float*)d_in[7];
    const float* W2r = (const float*)d_in[8];
    const float* W3l = (const float*)d_in[9];
    const float* b3  = (const float*)d_in[10];
    const float* W3r = (const float*)d_in[11];
    const float* Wlin = (const float*)d_in[12];
    const float* blin = (const float*)d_in[13];
    float* out = (float*)d_out;

    char* ws = (char*)d_ws;
    size_t off = 0;
    auto alloc = [&](size_t bytes) -> char* {
        char* p = ws + off;
        off = (off + bytes + 255) & ~(size_t)255;
        return p;
    };
    int* offsets = (int*)alloc((N_NODES + 1) * sizeof(int));
    int* cursor  = (int*)alloc(N_NODES * sizeof(int));
    int* deg     = (int*)alloc(N_NODES * sizeof(int));
    int* bsum    = (int*)alloc(64 * sizeof(int));
    int* goff    = (int*)alloc((NGRAPHS + 1) * sizeof(int));
    int* esrc    = (int*)alloc(N_EDGES * sizeof(int));
    unsigned short* h0   = (unsigned short*)alloc((size_t)N_NODES * 128 * 2);
    unsigned short* h1   = (unsigned short*)alloc((size_t)N_NODES * 128 * 2);
    unsigned short* h2   = (unsigned short*)alloc((size_t)N_NODES * 128 * 2);
    unsigned short* h3   = (unsigned short*)alloc((size_t)N_NODES * 128 * 2);
    unsigned short* aggb = (unsigned short*)alloc((size_t)N_NODES * 128 * 2);
    unsigned short* Wt   = (unsigned short*)alloc(3 * 256 * 128 * 2);
    float* pooled = (float*)alloc(NGRAPHS * 384 * sizeof(float));

    hipMemsetAsync(deg, 0, N_NODES * sizeof(int), stream);

    k_count<<<(N_EDGES + 255) / 256, 256, 0, stream>>>(dst, deg);
    k_scan1<<<40, 1024, 0, stream>>>(deg, offsets, bsum);
    k_scan3<<<40, 1024, 0, stream>>>(bsum, offsets, cursor);
    k_fill<<<(N_EDGES + 255) / 256, 256, 0, stream>>>(src, dst, cursor, esrc);
    k_goff<<<(N_NODES + 255) / 256, 256, 0, stream>>>(batch, goff);
    k_castx<<<(N_NODES * 64 + 255) / 256, 256, 0, stream>>>(x, h0);
    k_castw<<<384, 256, 0, stream>>>(W1l, W1r, W2l, W2r, W3l, W3r, Wt);

    k_agg<<<N_NODES / 4, 256, 0, stream>>>(h0, offsets, esrc, aggb);
    k_gemm<<<625, 256, 0, stream>>>(aggb, h0, Wt, b1, h1);
    k_agg<<<N_NODES / 4, 256, 0, stream>>>(h1, offsets, esrc, aggb);
    k_gemm<<<625, 256, 0, stream>>>(aggb, h1, Wt + 32768, b2, h2);
    k_agg<<<N_NODES / 4, 256, 0, stream>>>(h2, offsets, esrc, aggb);
    k_gemm<<<625, 256, 0, stream>>>(aggb, h2, Wt + 2 * 32768, b3, h3);

    k_pool<<<3 * NGRAPHS, 256, 0, stream>>>(h1, h2, h3, goff, pooled);
    k_final<<<NGRAPHS, 128, 0, stream>>>(pooled, Wlin, blin, out);
}